// Round 13
// baseline (70.982 us; speedup 1.0000x reference)
//
#include <hip/hip_runtime.h>
#include <hip/hip_fp16.h>
#include <hip/hip_cooperative_groups.h>

namespace cg = cooperative_groups;

#define NB   8
#define NDEP 64
#define KK   512
#define NP   12
#define NT   550
#define BWIN 40                    // per-bn tick band [floor(z)-20, +20)
#define L2E  1.4426950408889634f
#define OUTN (NB * NP * NT)        // 52800
#define NBLK 512                   // coop grid: guaranteed co-resident (2/CU @64KB pool)

// ws table layout (dwords):
//  [0..27]    w1a  = W1[0][j]*L2E
//  [28..55]   w1b  = W1[1][j]*L2E
//  [56..83]   b1s  = b1[j]*L2E
//  [84..251]  w2pk = half2(W2[j][2c], W2[j][2c+1])   (j*6+c)
//  [252..257] b2pk = half2(b2[2c], b2[2c+1])
//  [258..269] qtab = pscale[p]^2 * GAUSS_NORM

static __device__ __forceinline__ float fast_rcp(float x) {
    return __builtin_amdgcn_rcpf(x);
}
static __device__ __forceinline__ unsigned packh2(float a, float b) {
    __half2 h = __floats2half2_rn(a, b);
    return __builtin_bit_cast(unsigned, h);
}

static __device__ __forceinline__ void pack_weights(
    int tid,
    const float* __restrict__ W1, const float* __restrict__ b1,
    const float* __restrict__ W2, const float* __restrict__ b2,
    const float* __restrict__ pscale, float* __restrict__ wst)
{
    if (tid < 28) {
        wst[tid]      = W1[tid]      * L2E;
        wst[28 + tid] = W1[28 + tid] * L2E;
        wst[56 + tid] = b1[tid]      * L2E;
    }
    if (tid >= 64 && tid < 232) {              // 168 packed W2 entries
        const int e = tid - 64, j = e / 6, c = e - j * 6;
        ((unsigned*)(wst + 84))[e] = packh2(W2[j * NP + 2 * c], W2[j * NP + 2 * c + 1]);
    }
    if (tid >= 232 && tid < 238) {
        const int c = tid - 232;
        ((unsigned*)(wst + 252))[c] = packh2(b2[2 * c], b2[2 * c + 1]);
    }
    if (tid >= 238 && tid < 250) {
        const int p = tid - 238;
        wst[258 + p] = pscale[p] * pscale[p] * 3.9894228040143274f;
    }
}

// LDS row k at dword offset k*16 + (k>>4)*4 (16B pad per 16 rows): the S
// concurrent sub reads land on distinct bank groups.
template<int S>
static __device__ __forceinline__ void gather_partial(
    const float* __restrict__ wl, int lane, int t_lo, int off,
    float* __restrict__ ppart)
{
    constexpr int W = 64 / S;
    const int tw  = lane & (W - 1);
    const int sub = lane / W;
    const float tc = (float)t_lo + (float)tw + 0.5f;

    float acc[NP];
    #pragma unroll
    for (int p = 0; p < NP; ++p) acc[p] = 0.0f;

    #pragma unroll 4
    for (int i = 0; i < W; ++i) {
        const int k = sub * W + i;
        const int o = (k << 4) + ((k >> 4) << 2);
        const float4 r0 = *(const float4*)&wl[o];
        const float4 r1 = *(const float4*)&wl[o + 4];
        const float4 r2 = *(const float4*)&wl[o + 8];
        const float ez  = wl[o + 12];
        const float d   = tc - ez;
        const float g   = exp2f(-14.426950408889634f * d * d);   // exp(-10 d^2)
        acc[0]  = fmaf(r0.x, g, acc[0]);  acc[1]  = fmaf(r0.y, g, acc[1]);
        acc[2]  = fmaf(r0.z, g, acc[2]);  acc[3]  = fmaf(r0.w, g, acc[3]);
        acc[4]  = fmaf(r1.x, g, acc[4]);  acc[5]  = fmaf(r1.y, g, acc[5]);
        acc[6]  = fmaf(r1.z, g, acc[6]);  acc[7]  = fmaf(r1.w, g, acc[7]);
        acc[8]  = fmaf(r2.x, g, acc[8]);  acc[9]  = fmaf(r2.y, g, acc[9]);
        acc[10] = fmaf(r2.z, g, acc[10]); acc[11] = fmaf(r2.w, g, acc[11]);
    }

    #pragma unroll
    for (int msk = W; msk < 64; msk <<= 1) {
        #pragma unroll
        for (int p = 0; p < NP; ++p) acc[p] += __shfl_xor(acc[p], msk);
    }

    if (lane < W) {
        float* pp = ppart + (size_t)(off + lane) * NP;
        *(float4*)&pp[0] = make_float4(acc[0], acc[1],  acc[2],  acc[3]);
        *(float4*)&pp[4] = make_float4(acc[4], acc[5],  acc[6],  acc[7]);
        *(float4*)&pp[8] = make_float4(acc[8], acc[9],  acc[10], acc[11]);
    }
}

// The proven R11 wave body: vbid in [0, 1024) = bn*2 + khalf.
static __device__ __forceinline__ void sim_wave_body(
    int vbid, int tid,
    const float* __restrict__ ed,   const float* __restrict__ edraw,
    const float* __restrict__ ddraw,const float* __restrict__ udraw,
    const float* __restrict__ wst,  const float* __restrict__ dscale,
    const float* __restrict__ life, float* __restrict__ out,
    float (*rows)[1040], float (*part)[BWIN * NP], int2* hdr)
{
    const int lane = tid & 63;
    const int wid  = tid >> 6;             // 0..3
    const int bn   = vbid >> 1;
    const int g    = ((vbid & 1) << 2) | wid;   // k-group 0..7
    const int b    = bn >> 6;

    const float4 dep = ((const float4*)ed)[bn];
    const float  edr = edraw[bn];
    const int    k   = (g << 6) + lane;
    const float* dd  = ddraw + ((size_t)bn * KK + k) * 3;
    const float d0 = dd[0], d1 = dd[1], d2 = dd[2];
    const float u  = udraw[(size_t)bn * KK + k];

    const float nval  = dep.w * (1000000.0f / 22.4f);
    const float sigma = sqrtf(0.15f * nval);
    int ne = (int)(sigma * edr + nval);    // trunc == astype(int32)
    ne = min(max(ne, 0), KK);
    const int tb = (int)floorf(dep.z) - BWIN / 2;   // band start, in [30,479]
    const bool walive = ((g << 6) < ne);

    if (walive) {
        const float sqz     = sqrtf(dep.z);
        const float invLife = fast_rcp(life[0]);
        const float dS0 = dscale[0] * dscale[0];
        const float dS1 = dscale[1] * dscale[1];
        const float dS2 = dscale[2] * dscale[2];

        const float ez = fmaf(dS2 * d2, sqz, dep.z);
        const float ex = fmaf(dS0 * d0, sqz, dep.x);
        const float ey = fmaf(dS1 * d1, sqz, dep.y);
        const float prob = 1.0f - __expf(-ez * invLife);
        const float m = ((k < ne) && (prob > u)) ? 1.0f : 0.0f;

        const float*   w1a  = wst;
        const float*   w1b  = wst + 28;
        const float*   b1s  = wst + 56;
        const __half2* w2pk = (const __half2*)(wst + 84);
        const __half2* b2pk = (const __half2*)(wst + 252);
        const float*   qtab = wst + 258;

        __half2 pa0 = b2pk[0], pa1 = b2pk[1], pa2 = b2pk[2];
        __half2 pa3 = b2pk[3], pa4 = b2pk[4], pa5 = b2pk[5];
        #pragma unroll 4
        for (int j = 0; j < 28; ++j) {
            const float lg  = fmaf(w1a[j], ex, fmaf(w1b[j], ey, b1s[j]));
            const float hjf = fast_rcp(1.0f + exp2f(-lg));
            const __half2 h2 = __float2half2_rn(hjf);
            pa0 = __hfma2(h2, w2pk[j * 6 + 0], pa0);
            pa1 = __hfma2(h2, w2pk[j * 6 + 1], pa1);
            pa2 = __hfma2(h2, w2pk[j * 6 + 2], pa2);
            pa3 = __hfma2(h2, w2pk[j * 6 + 3], pa3);
            pa4 = __hfma2(h2, w2pk[j * 6 + 4], pa4);
            pa5 = __hfma2(h2, w2pk[j * 6 + 5], pa5);
        }
        float pm[NP];
        { float2 f;
          f = __half22float2(pa0); pm[0] = f.x; pm[1] = f.y;
          f = __half22float2(pa1); pm[2] = f.x; pm[3] = f.y;
          f = __half22float2(pa2); pm[4] = f.x; pm[5] = f.y;
          f = __half22float2(pa3); pm[6] = f.x; pm[7] = f.y;
          f = __half22float2(pa4); pm[8] = f.x; pm[9] = f.y;
          f = __half22float2(pa5); pm[10] = f.x; pm[11] = f.y; }

        float q[NP];
        #pragma unroll
        for (int p = 0; p < NP; ++p)
            q[p] = qtab[p] * m * fast_rcp(1.0f + exp2f(-pm[p] * L2E));

        float* wl = rows[wid];
        const int off = (lane << 4) + ((lane >> 4) << 2);
        *(float4*)&wl[off]     = make_float4(q[0], q[1],  q[2],  q[3]);
        *(float4*)&wl[off + 4] = make_float4(q[4], q[5],  q[6],  q[7]);
        *(float4*)&wl[off + 8] = make_float4(q[8], q[9],  q[10], q[11]);
        wl[off + 12] = ez;

        float ezmin = ez, ezmax = ez;
        #pragma unroll
        for (int msk = 1; msk < 64; msk <<= 1) {
            ezmin = fminf(ezmin, __shfl_xor(ezmin, msk));
            ezmax = fmaxf(ezmax, __shfl_xor(ezmax, msk));
        }
        const int fmin = (int)floorf(ezmin);
        const int fmax = (int)floorf(ezmax);
        const int need = fmax - fmin + 7;

        if (need <= 16) {
            const int t_lo = min(max(fmin - 3, tb), tb + BWIN - 16);
            gather_partial<4>(wl, lane, t_lo, t_lo - tb, part[wid]);
            if (lane == 0) hdr[wid] = make_int2(t_lo - tb, 16);
        } else {
            const int t_lo = min(max(fmin - 3, tb), tb + BWIN - 32);
            gather_partial<2>(wl, lane, t_lo, t_lo - tb, part[wid]);
            if (lane == 0) hdr[wid] = make_int2(t_lo - tb, 32);
        }
    } else {
        if (lane == 0) hdr[wid] = make_int2(0, 0);
    }
    __syncthreads();

    // block combine over 4 waves; one atomic per nonzero band element
    for (int idx = tid; idx < BWIN * NP; idx += 256) {
        const int t_rel = idx / NP;
        const int p     = idx - t_rel * NP;
        float s = 0.0f;
        #pragma unroll
        for (int w = 0; w < 4; ++w) {
            const int2 h  = hdr[w];
            const int  dt = t_rel - h.x;
            if ((unsigned)dt < (unsigned)h.y)
                s += part[w][t_rel * NP + p];
        }
        if (s != 0.0f)
            atomicAdd(&out[((size_t)b * NP + p) * NT + (tb + t_rel)], s);
    }
}

// ---------------- cooperative single-dispatch kernel ----------------
__global__ __launch_bounds__(256) void next_sim_coop(
    const float* __restrict__ ed,   const float* __restrict__ edraw,
    const float* __restrict__ ddraw,const float* __restrict__ udraw,
    const float* __restrict__ W1, const float* __restrict__ b1,
    const float* __restrict__ W2, const float* __restrict__ b2,
    const float* __restrict__ dscale, const float* __restrict__ pscale,
    const float* __restrict__ life,
    float* __restrict__ wst, float* __restrict__ out)
{
    __shared__ float rows[4][1040];
    __shared__ float part[4][BWIN * NP];
    __shared__ int2  hdr[4];

    const int tid = threadIdx.x;
    const int bid = blockIdx.x;

    // phase A: zero out + (block 0) pack weights
    {
        const int zi = bid * 256 + tid;
        if (zi < OUTN) out[zi] = 0.0f;
        if (bid == 0) pack_weights(tid, W1, b1, W2, b2, pscale, wst);
    }
    cg::this_grid().sync();

    // phase B: two virtual bids per block
    sim_wave_body(bid, tid, ed, edraw, ddraw, udraw, wst, dscale, life, out,
                  rows, part, hdr);
    __syncthreads();
    sim_wave_body(bid + NBLK, tid, ed, edraw, ddraw, udraw, wst, dscale, life, out,
                  rows, part, hdr);
}

// ---------------- fallback two-dispatch path (proven R11) ----------------
__global__ __launch_bounds__(256) void init_kernel(
    const float* __restrict__ W1, const float* __restrict__ b1,
    const float* __restrict__ W2, const float* __restrict__ b2,
    const float* __restrict__ pscale,
    float* __restrict__ ws, float* __restrict__ out, int out_size)
{
    const int idx = blockIdx.x * 256 + threadIdx.x;
    for (int i = idx; i < out_size; i += gridDim.x * 256) out[i] = 0.0f;
    if (blockIdx.x == 0) pack_weights(threadIdx.x, W1, b1, W2, b2, pscale, ws);
}

__global__ __launch_bounds__(256) void next_sim_wave(
    const float* __restrict__ ed,   const float* __restrict__ edraw,
    const float* __restrict__ ddraw,const float* __restrict__ udraw,
    const float* __restrict__ wst,  const float* __restrict__ dscale,
    const float* __restrict__ life, float* __restrict__ out)
{
    __shared__ float rows[4][1040];
    __shared__ float part[4][BWIN * NP];
    __shared__ int2  hdr[4];
    sim_wave_body(blockIdx.x, threadIdx.x, ed, edraw, ddraw, udraw, wst,
                  dscale, life, out, rows, part, hdr);
}

extern "C" void kernel_launch(void* const* d_in, const int* in_sizes, int n_in,
                              void* d_out, int out_size, void* d_ws, size_t ws_size,
                              hipStream_t stream) {
    const float* ed     = (const float*)d_in[0];
    const float* edraw  = (const float*)d_in[1];
    const float* ddraw  = (const float*)d_in[2];
    const float* udraw  = (const float*)d_in[3];
    const float* W1     = (const float*)d_in[4];
    const float* b1     = (const float*)d_in[5];
    const float* W2     = (const float*)d_in[6];
    const float* b2     = (const float*)d_in[7];
    const float* dscale = (const float*)d_in[8];
    const float* pscale = (const float*)d_in[9];
    const float* life   = (const float*)d_in[10];
    float* ws  = (float*)d_ws;
    float* out = (float*)d_out;

    void* params[] = {
        (void*)&ed, (void*)&edraw, (void*)&ddraw, (void*)&udraw,
        (void*)&W1, (void*)&b1, (void*)&W2, (void*)&b2,
        (void*)&dscale, (void*)&pscale, (void*)&life,
        (void*)&ws, (void*)&out
    };
    hipError_t err = hipLaunchCooperativeKernel((const void*)next_sim_coop,
                                                dim3(NBLK), dim3(256),
                                                params, 0, stream);
    if (err != hipSuccess) {
        // deterministic fallback: proven two-dispatch path
        init_kernel<<<64, 256, 0, stream>>>(W1, b1, W2, b2, pscale, ws, out, out_size);
        next_sim_wave<<<NB * NDEP * 2, 256, 0, stream>>>(
            ed, edraw, ddraw, udraw, ws, dscale, life, out);
    }
}

// Round 14
// 20.238 us; speedup vs baseline: 3.5074x; 3.5074x over previous
//
#include <hip/hip_runtime.h>

#define NB   8
#define NDEP 64
#define KK   512
#define NP   12
#define NT   550
#define L2E  1.4426950408889634f
#define GN   3.9894228040143274f

static __device__ __forceinline__ float fast_rcp(float x) {
    return __builtin_amdgcn_rcpf(x);
}

// LDS row k at dword offset k*16 + (k>>4)*4 (16B pad per 16 rows): the S
// concurrent sub reads land on distinct bank groups.
// Gather over this wave's 64 rows, shuffle-combine subs, per-wave atomics.
template<int S>
static __device__ __forceinline__ void gather_reduce(
    const float* __restrict__ wl, int lane, int t_lo, int b,
    float* __restrict__ out)
{
    constexpr int W = 64 / S;
    const int tw  = lane & (W - 1);
    const int sub = lane / W;
    const float tc = (float)t_lo + (float)tw + 0.5f;

    float acc[NP];
    #pragma unroll
    for (int p = 0; p < NP; ++p) acc[p] = 0.0f;

    #pragma unroll 4
    for (int i = 0; i < W; ++i) {
        const int k = sub * W + i;
        const int o = (k << 4) + ((k >> 4) << 2);
        const float4 r0 = *(const float4*)&wl[o];
        const float4 r1 = *(const float4*)&wl[o + 4];
        const float4 r2 = *(const float4*)&wl[o + 8];
        const float ez  = wl[o + 12];
        const float d   = tc - ez;
        const float g   = exp2f(-14.426950408889634f * d * d);   // exp(-10 d^2)
        acc[0]  = fmaf(r0.x, g, acc[0]);  acc[1]  = fmaf(r0.y, g, acc[1]);
        acc[2]  = fmaf(r0.z, g, acc[2]);  acc[3]  = fmaf(r0.w, g, acc[3]);
        acc[4]  = fmaf(r1.x, g, acc[4]);  acc[5]  = fmaf(r1.y, g, acc[5]);
        acc[6]  = fmaf(r1.z, g, acc[6]);  acc[7]  = fmaf(r1.w, g, acc[7]);
        acc[8]  = fmaf(r2.x, g, acc[8]);  acc[9]  = fmaf(r2.y, g, acc[9]);
        acc[10] = fmaf(r2.z, g, acc[10]); acc[11] = fmaf(r2.w, g, acc[11]);
    }

    #pragma unroll
    for (int msk = W; msk < 64; msk <<= 1) {
        #pragma unroll
        for (int p = 0; p < NP; ++p) acc[p] += __shfl_xor(acc[p], msk);
    }

    if (lane < W) {
        float* ob = out + ((size_t)b * NP) * NT + (t_lo + tw);
        #pragma unroll
        for (int p = 0; p < NP; ++p) atomicAdd(&ob[p * NT], acc[p]);
    }
}

__global__ __launch_bounds__(256) void next_sim_wave(
    const float* __restrict__ ed,      // (8,64,4) x,y,z,E
    const float* __restrict__ edraw,   // (8,64)
    const float* __restrict__ ddraw,   // (8,64,512,3)
    const float* __restrict__ udraw,   // (8,64,512)
    const float* __restrict__ W1, const float* __restrict__ b1,
    const float* __restrict__ W2, const float* __restrict__ b2,
    const float* __restrict__ dscale, const float* __restrict__ pscale,
    const float* __restrict__ life,
    float* __restrict__ out)           // (8,12,550)
{
    __shared__ float rows[4][1040];    // per-wave private f32 rows (16.6 KB)

    const int tid  = threadIdx.x;
    const int lane = tid & 63;
    const int wid  = tid >> 6;             // 0..3
    const int bid  = blockIdx.x;           // 1024 blocks: bn*2 + khalf
    const int bn   = bid >> 1;
    const int g    = ((bid & 1) << 2) | wid;   // k-group 0..7
    const int b    = bn >> 6;

    // hoisted per-lane loads
    const float4 dep = ((const float4*)ed)[bn];
    const float  edr = edraw[bn];
    const int    k   = (g << 6) + lane;
    const float* dd  = ddraw + ((size_t)bn * KK + k) * 3;
    const float d0 = dd[0], d1 = dd[1], d2 = dd[2];
    const float u  = udraw[(size_t)bn * KK + k];

    // wave-uniform header
    const float nval  = dep.w * (1000000.0f / 22.4f);
    const float sigma = sqrtf(0.15f * nval);
    int ne = (int)(sigma * edr + nval);    // trunc == astype(int32)
    ne = min(max(ne, 0), KK);
    if ((g << 6) >= ne) return;            // dead wave: early exit

    const float sqz     = sqrtf(dep.z);
    const float invLife = fast_rcp(life[0]);
    const float dS0 = dscale[0] * dscale[0];
    const float dS1 = dscale[1] * dscale[1];
    const float dS2 = dscale[2] * dscale[2];

    const float ez = fmaf(dS2 * d2, sqz, dep.z);
    const float ex = fmaf(dS0 * d0, sqz, dep.x);
    const float ey = fmaf(dS1 * d1, sqz, dep.y);
    const float prob = 1.0f - __expf(-ez * invLife);
    const float m = ((k < ne) && (prob > u)) ? 1.0f : 0.0f;

    // MLP, all f32; weights via uniform-index global loads (s_load, L2-hot)
    float pm[NP];
    #pragma unroll
    for (int p = 0; p < NP; ++p) pm[p] = b2[p];
    #pragma unroll 4
    for (int j = 0; j < 28; ++j) {
        const float lg = fmaf(W1[j], ex, fmaf(W1[28 + j], ey, b1[j]));
        const float hj = fast_rcp(1.0f + exp2f(-lg * L2E));
        #pragma unroll
        for (int p = 0; p < NP; ++p) pm[p] = fmaf(hj, W2[j * NP + p], pm[p]);
    }
    const float gm = GN * m;               // fold GAUSS_NORM + mask
    float q[NP];
    #pragma unroll
    for (int p = 0; p < NP; ++p)
        q[p] = pscale[p] * pscale[p] * gm * fast_rcp(1.0f + exp2f(-pm[p] * L2E));

    // this lane's f32 row into the wave-private LDS region
    float* wl = rows[wid];
    const int off = (lane << 4) + ((lane >> 4) << 2);
    *(float4*)&wl[off]     = make_float4(q[0], q[1],  q[2],  q[3]);
    *(float4*)&wl[off + 4] = make_float4(q[4], q[5],  q[6],  q[7]);
    *(float4*)&wl[off + 8] = make_float4(q[8], q[9],  q[10], q[11]);
    wl[off + 12] = ez;

    // wave ez min/max -> adaptive window
    float ezmin = ez, ezmax = ez;
    #pragma unroll
    for (int msk = 1; msk < 64; msk <<= 1) {
        ezmin = fminf(ezmin, __shfl_xor(ezmin, msk));
        ezmax = fmaxf(ezmax, __shfl_xor(ezmax, msk));
    }
    const int fmin = (int)floorf(ezmin);
    const int fmax = (int)floorf(ezmax);
    const int need = fmax - fmin + 7;      // +-3 ticks around [fmin, fmax]

    if (need <= 16) {
        const int t_lo = min(max(fmin - 3, 0), NT - 16);
        gather_reduce<4>(wl, lane, t_lo, b, out);
    } else {
        const int t_lo = min(max(fmin - 3, 0), NT - 32);
        gather_reduce<2>(wl, lane, t_lo, b, out);
    }
}

extern "C" void kernel_launch(void* const* d_in, const int* in_sizes, int n_in,
                              void* d_out, int out_size, void* d_ws, size_t ws_size,
                              hipStream_t stream) {
    const float* ed     = (const float*)d_in[0];
    const float* edraw  = (const float*)d_in[1];
    const float* ddraw  = (const float*)d_in[2];
    const float* udraw  = (const float*)d_in[3];
    const float* W1     = (const float*)d_in[4];
    const float* b1     = (const float*)d_in[5];
    const float* W2     = (const float*)d_in[6];
    const float* b2     = (const float*)d_in[7];
    const float* dscale = (const float*)d_in[8];
    const float* pscale = (const float*)d_in[9];
    const float* life   = (const float*)d_in[10];
    float* out = (float*)d_out;

    hipMemsetAsync(d_out, 0, (size_t)out_size * sizeof(float), stream);
    next_sim_wave<<<NB * NDEP * 2, 256, 0, stream>>>(
        ed, edraw, ddraw, udraw, W1, b1, W2, b2, dscale, pscale, life, out);
}